// Round 9
// baseline (182.085 us; speedup 1.0000x reference)
//
#include <hip/hip_runtime.h>
#include <hip/hip_fp16.h>

#define S_LEN   524288
#define IN_D    22
#define HID     9
#define NTAG    4
#define CHUNK   64
#define BURN    32
#define NCHUNK  (S_LEN / CHUNK)   // 8192
#define WPB     4
#define PF      8                 // scan prefetch ring depth (steps)

#define PAD_LO  48
#define PAD_HI  8
#define XGP_ROWS ((size_t)PAD_LO + S_LEN + PAD_HI)
#define XGP_HALFS (XGP_ROWS * 36)
#define H_HALFS   ((size_t)S_LEN * HID)
#define WS_NEED   ((XGP_HALFS + H_HALFS) * 2)

// ---- DPP quad_perm helpers ----
template <int PAT>
__device__ __forceinline__ float qperm(float v) {
  return __int_as_float(__builtin_amdgcn_update_dpp(
      0, __float_as_int(v), PAT, 0xF, 0xF, true));
}
// rot+1=0x39, rot+2=0x4E, rot+3=0x93, xor1=0xB1

// =====================  Kernel 1: gate pre-activation GEMM v5  ==============
// thread = timestep; weights via wave-uniform s_loads; compute fp32.
// Epilogue: stage 36 halfs/thread in LDS, then WAVE-COALESCED uint2 stores
// (fixes round-8's 3.5x sector write amplification: 134MB -> 38MB).
#define GT4 256   // timesteps per block
__global__ __launch_bounds__(256, 4)
void xg_gemm5(const float* __restrict__ x, const float* __restrict__ w_ih,
              const float* __restrict__ b_ih, const float* __restrict__ b_hh,
              __half* __restrict__ xgp)
{
  __shared__ __align__(16) float xs[GT4 * IN_D];   // 22528 B (>= 18432 out)
  const int tid = threadIdx.x;
  const long tb = (long)blockIdx.x * GT4;

  const float4* gx = (const float4*)(x + tb * IN_D);   // 16B-aligned (256*88)
  float4* lx = (float4*)xs;
#pragma unroll
  for (int i = 0; i < 6; ++i) {
    const int idx = i * 256 + tid;
    if (idx < (GT4 * IN_D / 4)) lx[idx] = gx[idx];
  }
  __syncthreads();

  float xv[IN_D];
  const float* xr = xs + tid * IN_D;
#pragma unroll
  for (int k = 0; k < IN_D; ++k) xv[k] = xr[k];
  __syncthreads();   // all rows consumed -> xs reusable as output staging

  unsigned pk[18];
#pragma unroll 1
  for (int grp = 0; grp < 9; ++grp) {
    float o4[4];
#pragma unroll
    for (int j = 0; j < 4; ++j) {
      const int r = grp * 4 + j;
      const float* wr = w_ih + r * IN_D;          // uniform -> s_load
      float a0 = b_ih[r] + b_hh[r], a1 = 0.f;     // uniform -> SALU
#pragma unroll
      for (int k = 0; k < IN_D; k += 2) {
        a0 = fmaf(xv[k],     wr[k],     a0);      // 1 SGPR operand each
        a1 = fmaf(xv[k + 1], wr[k + 1], a1);
      }
      const float mex = (r >= 18 && r < 27) ? -2.885390082f : -1.442695041f;
      o4[j] = (a0 + a1) * mex;
    }
    pk[grp * 2]     = __builtin_bit_cast(unsigned, __floats2half2_rn(o4[0], o4[1]));
    pk[grp * 2 + 1] = __builtin_bit_cast(unsigned, __floats2half2_rn(o4[2], o4[3]));
  }

  // stage rows (72B each) in LDS, then coalesced copy-out (512B/wave-instr)
  uint2* lo = (uint2*)xs;
#pragma unroll
  for (int i = 0; i < 9; ++i)
    lo[tid * 9 + i] = make_uint2(pk[2 * i], pk[2 * i + 1]);
  __syncthreads();
  const uint2* ls = (const uint2*)xs;
  uint2* go = (uint2*)(xgp + tb * 36);   // tb*72 B: 8B-aligned
#pragma unroll
  for (int i = 0; i < 9; ++i)
    go[i * 256 + tid] = ls[i * 256 + tid];
}

// =====================  Kernel 2: serial scan v5  ===========================
// CHUNK=64, BURN=32, 2 chunks/wave -> 4096 waves (4/SIMD, 8 chains/SIMD).
// h-broadcast via ds_bpermute (LDS crossbar pipe, parallel with VALU)
// instead of 9 v_readlane on the VALU pipe.
// xgp rows -48..-1 are 0x7B7B: huge positive prescaled preact -> gates 0
// -> exact h=c=0 at chunk entry (incl. chunk 0).
__global__ __launch_bounds__(256, 4)
void lstm_scan5(const __half* __restrict__ xgp,
                const float* __restrict__ w_hh,
                __half* __restrict__ hout)
{
  const int tid  = threadIdx.x;
  const int wv   = tid >> 6;
  const int lane = tid & 63;
  const int u = lane >> 2, g = lane & 3;
  const bool act = (u < HID);
  const int row  = act ? (g * HID + u) : 0;
  const int ll   = (lane < 36) ? (g * HID + u) : 35;   // gate-major xgp index
  const float smul = (g == 2) ? 2.f : 1.f;
  const float soff = (g == 2) ? -1.f : 0.f;
  const float mexp = (g == 2) ? -2.885390082f : -1.442695041f;

  float whh[HID];
#pragma unroll
  for (int k = 0; k < HID; ++k)
    whh[k] = (act ? w_hh[row * HID + k] : 0.f) * mexp;

  int bidx[HID];   // bpermute byte addrs: pull from lane 4k
#pragma unroll
  for (int k = 0; k < HID; ++k) bidx[k] = 16 * k;

  const int gw = (int)blockIdx.x * WPB + wv;       // 0..4095
  const int startA = gw * (2 * CHUNK);
  const int startB = startA + CHUNK;
  const long t0A = (long)startA - BURN;            // >= -32 (pad covers)
  const long t0B = (long)startB - BURN;
  const __half* gA = xgp + t0A * 36 + ll;
  const __half* gB = xgp + t0B * 36 + ll;

  __half xqA[PF], xqB[PF];
#pragma unroll
  for (int j = 0; j < PF; ++j) { xqA[j] = gA[j * 36]; xqB[j] = gB[j * 36]; }

  float shA[HID], shB[HID];
#pragma unroll
  for (int k = 0; k < HID; ++k) { shA[k] = 0.f; shB[k] = 0.f; }
  float cstA = 0.f, cstB = 0.f;

#define STEP(xq, gptr, sh, cst, hv, S)                                  \
  {                                                                     \
    float a0 = __half2float(xq[j]);                                     \
    xq[j] = gptr[(S + PF) * 36];                                        \
    float a1 = 0.f;                                                     \
    _Pragma("unroll")                                                   \
    for (int k = 0; k < HID; ++k) {                                     \
      if (k & 1) a1 = fmaf(sh[k], whh[k], a1);                          \
      else       a0 = fmaf(sh[k], whh[k], a0);                          \
    }                                                                   \
    const float pre = a0 + a1;                                          \
    const float ex  = __builtin_amdgcn_exp2f(pre);                      \
    const float gv  = fmaf(__builtin_amdgcn_rcpf(1.f + ex), smul, soff);\
    const float fg = qperm<0x39>(gv);                                   \
    const float gg = qperm<0x4E>(gv);                                   \
    const float og = qperm<0x93>(gv);                                   \
    cst = fmaf(fg, cst, gv * gg);                                       \
    const float e2 = __builtin_amdgcn_exp2f(cst * -2.885390082f);       \
    const float th = fmaf(__builtin_amdgcn_rcpf(1.f + e2), 2.f, -1.f);  \
    hv = og * th;                                                       \
    _Pragma("unroll")                                                   \
    for (int k = 0; k < HID; ++k)                                       \
      sh[k] = __int_as_float(__builtin_amdgcn_ds_bpermute(              \
          bidx[k], __float_as_int(hv)));                                \
  }

  const int NSTEP = CHUNK + BURN;                  // 96, uniform all chunks
  for (int b = 0; b < NSTEP / PF; ++b) {
    const int sb = b * PF;
    const bool outp = sb >= BURN;                  // BURN % PF == 0
#pragma unroll
    for (int j = 0; j < PF; ++j) {
      const int s = sb + j;
      float hvA, hvB;
      STEP(xqA, gA, shA, cstA, hvA, s)
      STEP(xqB, gB, shB, cstB, hvB, s)
      if (outp && g == 0 && act) {
        hout[(long)(startA + s - BURN) * HID + u] = __float2half(hvA);
        hout[(long)(startB + s - BURN) * HID + u] = __float2half(hvB);
      }
    }
  }
#undef STEP
}

// =====================  Kernel 3: output head v2  ===========================
__global__ __launch_bounds__(256)
void head2(const __half* __restrict__ h, const float* __restrict__ w_out,
           const float* __restrict__ b_out, float* __restrict__ out)
{
  const long t = (long)blockIdx.x * 256 + threadIdx.x;   // exact grid
  const __half* hr = h + t * HID;
  float hv[HID];
#pragma unroll
  for (int k = 0; k < HID; ++k) hv[k] = __half2float(hr[k]);

  float a[NTAG];
#pragma unroll
  for (int tg = 0; tg < NTAG; ++tg) {
    a[tg] = b_out[tg];                      // uniform -> SGPR
#pragma unroll
    for (int k = 0; k < HID; ++k)
      a[tg] = fmaf(hv[k], w_out[tg * HID + k], a[tg]);
  }
  float m = fmaxf(fmaxf(a[0], a[1]), fmaxf(a[2], a[3]));
  float e0 = __builtin_amdgcn_exp2f((a[0] - m) * 1.442695041f);
  float e1 = __builtin_amdgcn_exp2f((a[1] - m) * 1.442695041f);
  float e2 = __builtin_amdgcn_exp2f((a[2] - m) * 1.442695041f);
  float e3 = __builtin_amdgcn_exp2f((a[3] - m) * 1.442695041f);
  const float lse = 0.69314718056f * __builtin_amdgcn_logf((e0 + e1) + (e2 + e3));
  float4 r;
  r.x = a[0] - m - lse; r.y = a[1] - m - lse;
  r.z = a[2] - m - lse; r.w = a[3] - m - lse;
  *(float4*)(out + t * NTAG) = r;
}

// =====================  Fallback: round-0 fused kernel (proven)  ============
#define FCHUNK  128
#define TILE    16
#define ROWF    24
#define TILEF   (TILE * ROWF)
#define NLOADS  (TILEF / 64)

__global__ __launch_bounds__(256, 4)
void lstm_chunk_scan(const float* __restrict__ x,
                     const float* __restrict__ w_ih,
                     const float* __restrict__ w_hh,
                     const float* __restrict__ b_ih,
                     const float* __restrict__ b_hh,
                     const float* __restrict__ w_out,
                     const float* __restrict__ b_out,
                     float* __restrict__ out)
{
  __shared__ __align__(16) float lds[WPB * 2 * TILEF];

  const int tid  = threadIdx.x;
  const int wv   = __builtin_amdgcn_readfirstlane(tid >> 6);
  const int lane = tid & 63;
  const int u    = lane >> 2;
  const int g    = lane & 3;
  const bool act = (u < HID);
  const int row  = act ? (g * HID + u) : 0;

  float wih[IN_D], whh[HID], wo[HID];
#pragma unroll
  for (int k = 0; k < IN_D; ++k) wih[k] = act ? w_ih[row * IN_D + k] : 0.f;
#pragma unroll
  for (int k = 0; k < HID; ++k)  whh[k] = act ? w_hh[row * HID + k] : 0.f;
  const float bias = act ? (b_ih[row] + b_hh[row]) : 0.f;
  const int orow = (lane < NTAG) ? lane : 0;
  float wo_b = b_out[orow];
#pragma unroll
  for (int k = 0; k < HID; ++k)  wo[k] = w_out[orow * HID + k];
  if (lane >= NTAG) { wo_b = 0.f; }

  const float mexp = (g == 2) ? -2.885390082f : -1.442695041f;
  const float smul = (g == 2) ? 2.f : 1.f;
  const float soff = (g == 2) ? -1.f : 0.f;

  const int chunk = __builtin_amdgcn_readfirstlane((int)blockIdx.x * WPB + wv);
  const int start = chunk * FCHUNK;
  const int t0    = (start >= BURN) ? (start - BURN) : 0;
  const int nstep = start + FCHUNK - t0;
  const int ntile = nstep / TILE;

  float* myl = lds + wv * 2 * TILEF;

  int goff[NLOADS];
#pragma unroll
  for (int cc = 0; cc < NLOADS; ++cc) {
    int slot = cc * 64 + lane;
    int r = slot / ROWF;
    int col = slot - r * ROWF;
    if (col >= IN_D) col = IN_D - 1;
    goff[cc] = r * IN_D + col;
  }
  const long XMAX = (long)S_LEN * IN_D - 1;

  float stage[NLOADS];
  {
    long tb = (long)t0 * IN_D;
#pragma unroll
    for (int cc = 0; cc < NLOADS; ++cc) {
      long gi = tb + goff[cc];
      if (gi > XMAX) gi = XMAX;
      stage[cc] = x[gi];
    }
#pragma unroll
    for (int cc = 0; cc < NLOADS; ++cc) myl[cc * 64 + lane] = stage[cc];
  }

  float sh[HID];
#pragma unroll
  for (int k = 0; k < HID; ++k) sh[k] = 0.f;
  float cst = 0.f;

  for (int ti = 0; ti < ntile; ++ti) {
    {
      long tb = (long)(t0 + (ti + 1) * TILE) * IN_D;
#pragma unroll
      for (int cc = 0; cc < NLOADS; ++cc) {
        long gi = tb + goff[cc];
        if (gi > XMAX) gi = XMAX;
        stage[cc] = x[gi];
      }
    }

    const float* rb = myl + (ti & 1) * TILEF;
    const int tbase = t0 + ti * TILE;
    const bool outp = (tbase >= start);

#pragma unroll
    for (int s = 0; s < TILE; ++s) {
      const float* xr = rb + s * ROWF;
      float xv[22];
      *(float4*)(&xv[0])  = *(const float4*)(xr + 0);
      *(float4*)(&xv[4])  = *(const float4*)(xr + 4);
      *(float4*)(&xv[8])  = *(const float4*)(xr + 8);
      *(float4*)(&xv[12]) = *(const float4*)(xr + 12);
      *(float4*)(&xv[16]) = *(const float4*)(xr + 16);
      *(float2*)(&xv[20]) = *(const float2*)(xr + 20);

      float a0 = bias, a1 = 0.f;
#pragma unroll
      for (int k = 0; k < IN_D; ++k) {
        if (k & 1) a1 = fmaf(xv[k], wih[k], a1);
        else       a0 = fmaf(xv[k], wih[k], a0);
      }
#pragma unroll
      for (int k = 0; k < HID; ++k) {
        if (k & 1) a1 = fmaf(sh[k], whh[k], a1);
        else       a0 = fmaf(sh[k], whh[k], a0);
      }
      float pre = a0 + a1;

      float ex = __builtin_amdgcn_exp2f(pre * mexp);
      float gv = fmaf(__builtin_amdgcn_rcpf(1.f + ex), smul, soff);

      float fg = qperm<0x39>(gv);
      float gg = qperm<0x4E>(gv);
      float og = qperm<0x93>(gv);
      cst = fmaf(fg, cst, gv * gg);
      float e2 = __builtin_amdgcn_exp2f(cst * -2.885390082f);
      float th = fmaf(__builtin_amdgcn_rcpf(1.f + e2), 2.f, -1.f);
      float hv = og * th;

#pragma unroll
      for (int k = 0; k < HID; ++k)
        sh[k] = __int_as_float(
            __builtin_amdgcn_readlane(__float_as_int(hv), 4 * k));

      if (outp) {
        float acc = wo_b;
#pragma unroll
        for (int k = 0; k < HID; ++k) acc = fmaf(sh[k], wo[k], acc);
        float m = fmaxf(acc, qperm<0xB1>(acc));
        m = fmaxf(m, qperm<0x4E>(m));
        float xm = acc - m;
        float ee = __builtin_amdgcn_exp2f(xm * 1.442695041f);
        float sm = ee + qperm<0xB1>(ee);
        sm = sm + qperm<0x4E>(sm);
        float res = fmaf(-0.69314718056f, __builtin_amdgcn_logf(sm), xm);
        if (lane < NTAG) out[(long)(tbase + s) * NTAG + lane] = res;
      }
    }

    float* wb = myl + ((ti + 1) & 1) * TILEF;
#pragma unroll
    for (int cc = 0; cc < NLOADS; ++cc) wb[cc * 64 + lane] = stage[cc];
  }
}

// ============================================================================
extern "C" void kernel_launch(void* const* d_in, const int* in_sizes, int n_in,
                              void* d_out, int out_size, void* d_ws, size_t ws_size,
                              hipStream_t stream) {
  (void)in_sizes; (void)n_in; (void)out_size;
  const float* x     = (const float*)d_in[0];
  const float* w_ih  = (const float*)d_in[1];
  const float* w_hh  = (const float*)d_in[2];
  const float* b_ih  = (const float*)d_in[3];
  const float* b_hh  = (const float*)d_in[4];
  const float* w_out = (const float*)d_in[5];
  const float* b_out = (const float*)d_in[6];
  float* out = (float*)d_out;

  if (ws_size >= WS_NEED) {
    __half* xgp_base = (__half*)d_ws;
    __half* xgp = xgp_base + (size_t)PAD_LO * 36;   // row t=0
    __half* h   = xgp_base + XGP_HALFS;
    // burn-in pad: huge positive prescaled preact -> all gates 0 -> h=c=0
    hipMemsetAsync(xgp_base, 0x7B, (size_t)PAD_LO * 36 * 2, stream);
    hipLaunchKernelGGL(xg_gemm5, dim3(S_LEN / GT4), dim3(256), 0, stream,
                       x, w_ih, b_ih, b_hh, xgp);
    hipLaunchKernelGGL(lstm_scan5, dim3(NCHUNK / 2 / WPB), dim3(256), 0, stream,
                       xgp, w_hh, h);
    hipLaunchKernelGGL(head2, dim3(S_LEN / 256), dim3(256), 0, stream,
                       h, w_out, b_out, out);
  } else {
    hipLaunchKernelGGL(lstm_chunk_scan, dim3((S_LEN / FCHUNK) / WPB), dim3(256),
                       0, stream, x, w_ih, w_hh, b_ih, b_hh, w_out, b_out, out);
  }
}

// Round 12
// 178.840 us; speedup vs baseline: 1.0181x; 1.0181x over previous
//
#include <hip/hip_runtime.h>
#include <hip/hip_fp16.h>

#define S_LEN   524288
#define IN_D    22
#define HID     9
#define NTAG    4
#define CHUNK   64
#define BURN    32
#define WPB     4                    // waves per block
#define TPB     (WPB * 2 * CHUNK)    // 512 output timesteps per block
#define ROWS    (TPB + BURN)         // 544 LDS gate-rows
#define NSTEP   (CHUNK + BURN)       // 96 scan steps per chunk

// ---- DPP quad_perm helper ----
template <int PAT>
__device__ __forceinline__ float qperm(float v) {
  return __int_as_float(__builtin_amdgcn_update_dpp(
      0, __float_as_int(v), PAT, 0xF, 0xF, true));
}
// rot+1=0x39, rot+2=0x4E, rot+3=0x93, xor1=0xB1

// One kernel, fully fused:
//  P1: gate pre-activations for the block's 544 rows -> LDS (half, 72B/row),
//      pre-scaled by mexp(g); rows t<0 get +BIG (gates->0 => exact h=c=0).
//  P2: serial scan (2 chunks/wave, 8 chains/SIMD) with the OUTPUT HEAD FUSED
//      INTO THE LOOP: after the bpermute broadcast every lane holds the full
//      h vector, so lanes 0-3 / 4-7 compute chunk A / B logits + log_softmax
//      (off the serial chain -> fills latency bubbles) and store directly.
//      No h storage anywhere => no LDS aliasing (round-10 bug eliminated).
__global__ __launch_bounds__(256, 4)
void lstm_fused2(const float* __restrict__ x,
                 const float* __restrict__ w_ih,
                 const float* __restrict__ w_hh,
                 const float* __restrict__ b_ih,
                 const float* __restrict__ b_hh,
                 const float* __restrict__ w_out,
                 const float* __restrict__ b_out,
                 float* __restrict__ out)
{
  __shared__ __align__(16) __half xg[ROWS * 36];   // 39168 B -> 4 blocks/CU

  const int tid = threadIdx.x;
  const long B0 = (long)blockIdx.x * TPB;

  // ================= P1: xg rows (thread = row) ============================
  for (int r = tid; r < ROWS; r += 256) {
    const long t = B0 - BURN + r;
    uint2* po = (uint2*)(xg + r * 36);             // r*72 B, 8B-aligned
    if (t < 0) {                                   // block 0 burn pad
#pragma unroll
      for (int i = 0; i < 9; ++i)
        po[i] = make_uint2(0x7B007B00u, 0x7B007B00u);   // half 57344.0
    } else {
      float xv[IN_D];
      const float* xr = x + t * IN_D;
#pragma unroll
      for (int c = 0; c < IN_D / 2; ++c)
        *(float2*)(&xv[2 * c]) = *(const float2*)(xr + 2 * c);  // 8B-aligned
#pragma unroll 1
      for (int grp = 0; grp < 9; ++grp) {
        float o4[4];
#pragma unroll
        for (int j = 0; j < 4; ++j) {
          const int rr = grp * 4 + j;
          const float* wr = w_ih + rr * IN_D;      // uniform -> s_load
          float a0 = b_ih[rr] + b_hh[rr], a1 = 0.f;
#pragma unroll
          for (int k = 0; k < IN_D; k += 2) {
            a0 = fmaf(xv[k],     wr[k],     a0);
            a1 = fmaf(xv[k + 1], wr[k + 1], a1);
          }
          const float mex = (rr >= 18 && rr < 27) ? -2.885390082f
                                                  : -1.442695041f;
          o4[j] = (a0 + a1) * mex;
        }
        uint2 pk;
        pk.x = __builtin_bit_cast(unsigned, __floats2half2_rn(o4[0], o4[1]));
        pk.y = __builtin_bit_cast(unsigned, __floats2half2_rn(o4[2], o4[3]));
        po[grp] = pk;
      }
    }
  }
  __syncthreads();

  // ================= P2: serial scan + fused head ==========================
  const int wv = tid >> 6, lane = tid & 63;
  const int u = lane >> 2, g = lane & 3;
  const bool act = (u < HID);
  const int row = act ? (g * HID + u) : 0;
  const int ll  = (lane < 36) ? (g * HID + u) : 35;     // gate-major index
  const float smul = (g == 2) ? 2.f : 1.f;
  const float soff = (g == 2) ? -1.f : 0.f;
  const float mexp = (g == 2) ? -2.885390082f : -1.442695041f;

  float whh[HID];
#pragma unroll
  for (int k = 0; k < HID; ++k)
    whh[k] = (act ? w_hh[row * HID + k] : 0.f) * mexp;

  int bidx[HID];                                   // bpermute: pull lane 4k
#pragma unroll
  for (int k = 0; k < HID; ++k) bidx[k] = 16 * k;

  // head per-lane constants: lanes 0-3 -> chunk A tag=lane; 4-7 -> chunk B
  const int tag = lane & 3;
  const bool isB = ((lane >> 2) == 1);
  const bool hd  = (lane < 8);
  float wo[HID];
#pragma unroll
  for (int k = 0; k < HID; ++k) wo[k] = w_out[tag * HID + k];
  const float wo_b = b_out[tag];
  const int ooff = (isB ? (CHUNK * NTAG) : 0) + tag;    // 0..3 or 256..259

  const int rA = wv * (2 * CHUNK);                 // LDS row base, chunk A
  const int rB = rA + CHUNK;                       // chunk B
  float* oW = out + (B0 + (long)wv * (2 * CHUNK)) * NTAG;   // wave out base

  float shA[HID], shB[HID];
#pragma unroll
  for (int k = 0; k < HID; ++k) { shA[k] = 0.f; shB[k] = 0.f; }
  float cstA = 0.f, cstB = 0.f;

#define STEP(rbase, sh, cst, S)                                           \
    {                                                                     \
      float a0 = __half2float(xg[(rbase + S) * 36 + ll]);                 \
      float a1 = 0.f;                                                     \
      _Pragma("unroll")                                                   \
      for (int k = 0; k < HID; ++k) {                                     \
        if (k & 1) a1 = fmaf(sh[k], whh[k], a1);                          \
        else       a0 = fmaf(sh[k], whh[k], a0);                          \
      }                                                                   \
      const float pre = a0 + a1;                                          \
      const float ex  = __builtin_amdgcn_exp2f(pre);                      \
      const float gv  = fmaf(__builtin_amdgcn_rcpf(1.f + ex), smul, soff);\
      const float fg = qperm<0x39>(gv);                                   \
      const float gg = qperm<0x4E>(gv);                                   \
      const float og = qperm<0x93>(gv);                                   \
      cst = fmaf(fg, cst, gv * gg);                                       \
      const float e2 = __builtin_amdgcn_exp2f(cst * -2.885390082f);       \
      const float th = fmaf(__builtin_amdgcn_rcpf(1.f + e2), 2.f, -1.f);  \
      const float hv = og * th;                                           \
      _Pragma("unroll")                                                   \
      for (int k = 0; k < HID; ++k)                                       \
        sh[k] = __int_as_float(__builtin_amdgcn_ds_bpermute(              \
            bidx[k], __float_as_int(hv)));                                \
    }

  for (int b = 0; b < NSTEP / 8; ++b) {
    const int sb = b * 8;
    const bool outp = sb >= BURN;                  // BURN % 8 == 0
#pragma unroll
    for (int j = 0; j < 8; ++j) {
      const int s = sb + j;
      STEP(rA, shA, cstA, s)
      STEP(rB, shB, cstB, s)
      if (outp) {
        // fused head: independent of the serial chain -> fills issue bubbles
        float hs[HID];
#pragma unroll
        for (int k = 0; k < HID; ++k) hs[k] = isB ? shB[k] : shA[k];
        float acc = wo_b;
#pragma unroll
        for (int k = 0; k < HID; ++k) acc = fmaf(hs[k], wo[k], acc);
        float m = fmaxf(acc, qperm<0xB1>(acc));
        m = fmaxf(m, qperm<0x4E>(m));
        const float xm = acc - m;
        const float e = __builtin_amdgcn_exp2f(xm * 1.442695041f);
        float sm = e + qperm<0xB1>(e);
        sm = sm + qperm<0x4E>(sm);
        const float res =
            fmaf(-0.69314718056f, __builtin_amdgcn_logf(sm), xm);
        if (hd) oW[(long)(s - BURN) * NTAG + ooff] = res;
      }
    }
  }
#undef STEP
}

// ============================================================================
extern "C" void kernel_launch(void* const* d_in, const int* in_sizes, int n_in,
                              void* d_out, int out_size, void* d_ws, size_t ws_size,
                              hipStream_t stream) {
  (void)in_sizes; (void)n_in; (void)out_size; (void)d_ws; (void)ws_size;
  const float* x     = (const float*)d_in[0];
  const float* w_ih  = (const float*)d_in[1];
  const float* w_hh  = (const float*)d_in[2];
  const float* b_ih  = (const float*)d_in[3];
  const float* b_hh  = (const float*)d_in[4];
  const float* w_out = (const float*)d_in[5];
  const float* b_out = (const float*)d_in[6];
  float* out = (float*)d_out;

  hipLaunchKernelGGL(lstm_fused2, dim3(S_LEN / TPB), dim3(256), 0, stream,
                     x, w_ih, w_hh, b_ih, b_hh, w_out, b_out, out);
}